// Round 11
// baseline (173.335 us; speedup 1.0000x reference)
//
#include <hip/hip_runtime.h>

#define N_NODES 100000
#define NUM_TYPES 8
#define FACTOR 0.125f      // 1/sqrt(64)

#define S_CHUNK 33344      // nodes per chunk; bins 130.3 KB + ctt4 16.3 KB < 160 KB LDS
#define C_CHUNKS 3         // 3*33344 = 100032 >= 100000  (sweeps: 4 -> 3, the lever)
#define THR 1024
#define B_TARGET 80        // grid = 3*80 = 240 blocks (<=1/CU); B % 8 == 0
#define NXCD 8             // blockIdx % 8 ~ XCD under round-robin dispatch

// ---------- Kernel 0: pack atom_type to u8 table + nibble table ----------
// tt  [C*S]   u8  — neighbor-type gathers (dense: 64 nodes/line)
// tt4 [C*S/2] u4x2 — center-type window staged into LDS by the fused kernel
__global__ __launch_bounds__(256) void type_pack_kernel(
    const int* __restrict__ atom_type,
    unsigned char* __restrict__ tt,
    unsigned char* __restrict__ tt4,
    int N)
{
    int i = blockIdx.x * blockDim.x + threadIdx.x;   // nibble-pair index
    if (i >= C_CHUNKS * S_CHUNK / 2) return;
    int n0 = 2 * i, n1 = 2 * i + 1;
    unsigned char t0 = (n0 < N) ? (unsigned char)atom_type[n0] : 0;
    unsigned char t1 = (n1 < N) ? (unsigned char)atom_type[n1] : 0;
    tt[n0] = t0;
    tt[n1] = t1;
    tt4[i] = (unsigned char)(t0 | (t1 << 4));
}

// ---------- Kernel 1: fused chunk-sum, C=3 sweeps, XCD-local grouping ----------
// Cost model (r0/5/6/8/10): dur ~= sweeps * E * 1.7cyc / nCU — issue-bound on the
// sweep loop, NOT fetch-bound (r10: FETCH 150->38 MB moved dur only 75->72).
// So C=4 -> C=3 cuts edge-visits 25%. Bins 130 KB; center types as nibbles in
// 16.3 KB LDS (u8 window no longer fits). Mapping keeps the 3 chunk-blocks of a
// segment on one XCD: x=blk&7, o=blk>>3, c=o%3, b=x*(B/8)+o/3 (r10: -4x FETCH).
__global__ __launch_bounds__(THR) void fused_chunk_sum_kernel(
    const int* __restrict__ centers,
    const int* __restrict__ neighbors,
    const float* __restrict__ eng,
    const unsigned char* __restrict__ tt,   // [C*S] u8 types (padded)
    const unsigned char* __restrict__ tt4,  // [C*S/2] nibble-packed types
    const float* __restrict__ scales,
    float* __restrict__ partials,           // [C_CHUNKS][B][S_CHUNK]
    int E, int B)
{
    __shared__ __align__(16) float bins[S_CHUNK];
    __shared__ __align__(4) unsigned char ctt4[S_CHUNK / 2];  // chunk center types (nibbles)
    __shared__ float s_scales[NUM_TYPES * NUM_TYPES];

    const int x = blockIdx.x & (NXCD - 1);   // XCD id (round-robin dispatch)
    const int o = blockIdx.x >> 3;           // ordinal within XCD
    const int c = o % C_CHUNKS;              // chunk
    const int b = x * (B >> 3) + o / C_CHUNKS;  // edge segment (B % 8 == 0)
    const int base = c * S_CHUNK;

    if (threadIdx.x < NUM_TYPES * NUM_TYPES)
        s_scales[threadIdx.x] = scales[threadIdx.x] * FACTOR;   // fold FACTOR

    float4* bins4 = (float4*)bins;
    for (int j = threadIdx.x; j < S_CHUNK / 4; j += THR)
        bins4[j] = make_float4(0.f, 0.f, 0.f, 0.f);
    // stage nibble window: S_CHUNK/2 bytes, base/2 = c*16672 (4-aligned) -> uint copies
    {
        const unsigned* src = (const unsigned*)(tt4 + c * (S_CHUNK / 2));
        unsigned* dst = (unsigned*)ctt4;
        for (int j = threadIdx.x; j < S_CHUNK / 8; j += THR) dst[j] = src[j];
    }
    __syncthreads();

    const int n4 = E >> 2;

    for (int i = b * THR + (int)threadIdx.x; i < n4; i += B * THR) {
        int4   cc = ((const int4*)centers)[i];
        int4   nn = ((const int4*)neighbors)[i];
        float4 e  = ((const float4*)eng)[i];

        unsigned j0 = (unsigned)(cc.x - base);
        unsigned j1 = (unsigned)(cc.y - base);
        unsigned j2 = (unsigned)(cc.z - base);
        unsigned j3 = (unsigned)(cc.w - base);

#define TC(J)  (int)((ctt4[(J) >> 1] >> (((J) & 1u) << 2)) & 7u)
        if (j0 < S_CHUNK)
            atomicAdd(&bins[j0], e.x * s_scales[TC(j0) * NUM_TYPES + (int)tt[nn.x]]);
        if (j1 < S_CHUNK)
            atomicAdd(&bins[j1], e.y * s_scales[TC(j1) * NUM_TYPES + (int)tt[nn.y]]);
        if (j2 < S_CHUNK)
            atomicAdd(&bins[j2], e.z * s_scales[TC(j2) * NUM_TYPES + (int)tt[nn.z]]);
        if (j3 < S_CHUNK)
            atomicAdd(&bins[j3], e.w * s_scales[TC(j3) * NUM_TYPES + (int)tt[nn.w]]);
    }

    // tail (E % 4) — dead for E = 6,400,000; b==0 occurs once per chunk
    // (x=0, o=0,1,2 -> c=0,1,2, b=0)
    if (b == 0) {
        for (int i = (n4 << 2) + (int)threadIdx.x; i < E; i += THR) {
            int cn = centers[i];
            unsigned j = (unsigned)(cn - base);
            if (j < S_CHUNK)
                atomicAdd(&bins[j], eng[i] * s_scales[TC(j) * NUM_TYPES + (int)tt[neighbors[i]]]);
        }
    }
#undef TC

    __syncthreads();
    float4* dst4 = (float4*)(partials + ((size_t)c * B + b) * S_CHUNK);
    for (int j = threadIdx.x; j < S_CHUNK / 4; j += THR) dst4[j] = bins4[j];
}

// ---------- Kernel 2: reduce segment partials (float4) ----------
__global__ __launch_bounds__(256) void reduce_kernel(
    const float* __restrict__ partials, float* __restrict__ out, int B, int N4)
{
    int t = blockIdx.x * blockDim.x + threadIdx.x;
    if (t >= N4) return;
    int n = t * 4;
    int c = n / S_CHUNK;
    int j = n - c * S_CHUNK;
    const float4* p = (const float4*)(partials + ((size_t)c * B) * S_CHUNK + j);
    float4 s = make_float4(0.f, 0.f, 0.f, 0.f);
    for (int b = 0; b < B; ++b) {
        float4 v = p[(size_t)b * (S_CHUNK / 4)];
        s.x += v.x; s.y += v.y; s.z += v.z; s.w += v.w;
    }
    ((float4*)out)[t] = s;
}

__global__ __launch_bounds__(256) void reduce_scalar_kernel(
    const float* __restrict__ partials, float* __restrict__ out, int B, int N)
{
    int n = blockIdx.x * blockDim.x + threadIdx.x;
    if (n >= N) return;
    int c = n / S_CHUNK;
    int j = n - c * S_CHUNK;
    const float* p = partials + ((size_t)c * B) * S_CHUNK + j;
    float s = 0.0f;
    for (int b = 0; b < B; ++b) s += p[(size_t)b * S_CHUNK];
    out[n] = s;
}

// ---------- Fallback (tiny workspace only): direct atomic scatter ----------
__global__ __launch_bounds__(256) void edge_sum_atomic_kernel(
    const int* __restrict__ centers, const int* __restrict__ neighbors,
    const float* __restrict__ eng, const int* __restrict__ atom_type,
    const float* __restrict__ scales, float* __restrict__ out, int E)
{
    __shared__ float s_scales[NUM_TYPES * NUM_TYPES];
    if (threadIdx.x < NUM_TYPES * NUM_TYPES) s_scales[threadIdx.x] = scales[threadIdx.x];
    __syncthreads();
    int tid = blockIdx.x * blockDim.x + threadIdx.x;
    int stride = gridDim.x * blockDim.x;
    for (int i = tid; i < E; i += stride) {
        int cn = centers[i];
        float v = eng[i] * s_scales[atom_type[cn] * NUM_TYPES + atom_type[neighbors[i]]] * FACTOR;
        unsafeAtomicAdd(&out[cn], v);
    }
}

extern "C" void kernel_launch(void* const* d_in, const int* in_sizes, int n_in,
                              void* d_out, int out_size, void* d_ws, size_t ws_size,
                              hipStream_t stream) {
    const int E = in_sizes[1];  // edge_eng element count
    const int N = in_sizes[2];  // atom_type element count
    const int* edge_index = (const int*)d_in[0];   // [2, E]
    const float* edge_eng = (const float*)d_in[1]; // [E, 1]
    const int* atom_type = (const int*)d_in[2];    // [N, 1]
    const float* scales = (const float*)d_in[3];   // [T, T]
    float* out = (float*)d_out;

    const int* centers = edge_index;
    const int* neighbors = edge_index + E;

    // ws layout: [tt: C*S u8][tt4: C*S/2 u8][partials: C*B*S_CHUNK floats]
    auto al = [](size_t v) { return (v + 255) & ~(size_t)255; };
    size_t tt_sz  = al((size_t)C_CHUNKS * S_CHUNK);               // ~100 KB
    size_t tt4_sz = al((size_t)C_CHUNKS * S_CHUNK / 2);           // ~50 KB
    size_t per_b  = (size_t)C_CHUNKS * S_CHUNK * sizeof(float);   // 400 128 B per segment

    int B = 0;
    if (N <= C_CHUNKS * S_CHUNK && ws_size > tt_sz + tt4_sz)
        B = (int)((ws_size - tt_sz - tt4_sz) / per_b);
    if (B > B_TARGET) B = B_TARGET;
    B &= ~7;   // XCD-local mapping requires B % 8 == 0

    if (B >= 8) {
        unsigned char* tt  = (unsigned char*)d_ws;
        unsigned char* tt4 = (unsigned char*)d_ws + tt_sz;
        float* partials    = (float*)((char*)d_ws + tt_sz + tt4_sz);
        type_pack_kernel<<<(C_CHUNKS * S_CHUNK / 2 + 255) / 256, 256, 0, stream>>>(
            atom_type, tt, tt4, N);
        fused_chunk_sum_kernel<<<C_CHUNKS * B, THR, 0, stream>>>(
            centers, neighbors, edge_eng, tt, tt4, scales, partials, E, B);
        if ((N & 3) == 0)
            reduce_kernel<<<(N / 4 + 255) / 256, 256, 0, stream>>>(partials, out, B, N / 4);
        else
            reduce_scalar_kernel<<<(N + 255) / 256, 256, 0, stream>>>(partials, out, B, N);
    } else {
        hipMemsetAsync(d_out, 0, (size_t)out_size * sizeof(float), stream);
        edge_sum_atomic_kernel<<<2048, 256, 0, stream>>>(
            centers, neighbors, edge_eng, atom_type, scales, out, E);
    }
}

// Round 12
// 160.316 us; speedup vs baseline: 1.0812x; 1.0812x over previous
//
#include <hip/hip_runtime.h>

#define N_NODES 100000
#define NUM_TYPES 8
#define FACTOR 0.125f      // 1/sqrt(64)

#define S_CHUNK 25600      // nodes per chunk; bins 100 KB + full tt4 50 KB = 153.9 KB LDS
#define C_CHUNKS 4         // 4*25600 = 102400 >= 100000
#define THR 1024
#define B_TARGET 64        // grid = 4*64 = 256 blocks (1/CU)
#define NXCD 8             // blockIdx % 8 ~ XCD under round-robin dispatch

// ---------- Kernel 0: pack atom_type into nibble table (50 KB) ----------
// tt4[i] holds types of nodes 2i (lo nibble) and 2i+1 (hi nibble). The fused
// kernel stages the WHOLE table in LDS -> zero global random access in the loop.
__global__ __launch_bounds__(256) void type_pack_kernel(
    const int* __restrict__ atom_type, unsigned char* __restrict__ tt4, int N)
{
    int i = blockIdx.x * blockDim.x + threadIdx.x;   // nibble-pair index
    if (i >= C_CHUNKS * S_CHUNK / 2) return;
    int n0 = 2 * i, n1 = 2 * i + 1;
    unsigned char t0 = (n0 < N) ? (unsigned char)atom_type[n0] : 0;
    unsigned char t1 = (n1 < N) ? (unsigned char)atom_type[n1] : 0;
    tt4[i] = (unsigned char)(t0 | (t1 << 4));
}

// ---------- Kernel 1: fused chunk-sum, all-LDS type lookups ----------
// Cost model (r0/5/6/8/10/11): dur ~= sweeps * E * cyc_per_visit / nCU, issue-
// bound (NOT fetch-bound: r10 cut FETCH 150->38 MB for only -3 us). r10 ran
// 1.73 cyc/visit with a global u8 gather per in-chunk edge; the lean r2 loop
// (no gathers) ran 1.24. This version moves BOTH type lookups to LDS (full
// 50 KB nibble table resident next to the 100 KB bins): the sweep loop's
// random traffic is now 100% LDS (random u8 ~ 2 lanes/bank = free, m136),
// VMEM carries only the 3 coalesced streams.
// XCD-local grouping (r10, -4x FETCH): x=blk&7, o=blk>>3, c=o&3, b=x*(B/8)+(o>>2).
__global__ __launch_bounds__(THR) void fused_chunk_sum_kernel(
    const int* __restrict__ centers,
    const int* __restrict__ neighbors,
    const float* __restrict__ eng,
    const unsigned char* __restrict__ tt4,  // [C*S/2] nibble-packed types (padded)
    const float* __restrict__ scales,
    float* __restrict__ partials,           // [C_CHUNKS][B][S_CHUNK]
    int E, int B)
{
    __shared__ __align__(16) float bins[S_CHUNK];
    __shared__ __align__(16) unsigned char s_tt4[C_CHUNKS * S_CHUNK / 2];  // 50 KB
    __shared__ float s_scales[NUM_TYPES * NUM_TYPES];

    const int x = blockIdx.x & (NXCD - 1);   // XCD id (round-robin dispatch)
    const int o = blockIdx.x >> 3;           // ordinal within XCD
    const int c = o & 3;                     // chunk
    const int b = x * (B >> 3) + (o >> 2);   // edge segment (B % 8 == 0)
    const int base = c * S_CHUNK;

    if (threadIdx.x < NUM_TYPES * NUM_TYPES)
        s_scales[threadIdx.x] = scales[threadIdx.x] * FACTOR;   // fold FACTOR

    float4* bins4 = (float4*)bins;
    for (int j = threadIdx.x; j < S_CHUNK / 4; j += THR)
        bins4[j] = make_float4(0.f, 0.f, 0.f, 0.f);
    // stage full nibble table: 51 200 B = 3200 uint4
    {
        const uint4* src = (const uint4*)tt4;
        uint4* dst = (uint4*)s_tt4;
        for (int j = threadIdx.x; j < C_CHUNKS * S_CHUNK / 2 / 16; j += THR)
            dst[j] = src[j];
    }
    __syncthreads();

    const int n4 = E >> 2;

// type of global node index G from the LDS nibble table
#define TY(G)  (int)((s_tt4[(unsigned)(G) >> 1] >> (((unsigned)(G) & 1u) << 2)) & 7u)

    for (int i = b * THR + (int)threadIdx.x; i < n4; i += B * THR) {
        int4   cc = ((const int4*)centers)[i];
        int4   nn = ((const int4*)neighbors)[i];
        float4 e  = ((const float4*)eng)[i];

        unsigned j0 = (unsigned)(cc.x - base);
        unsigned j1 = (unsigned)(cc.y - base);
        unsigned j2 = (unsigned)(cc.z - base);
        unsigned j3 = (unsigned)(cc.w - base);

        if (j0 < S_CHUNK)
            atomicAdd(&bins[j0], e.x * s_scales[TY(cc.x) * NUM_TYPES + TY(nn.x)]);
        if (j1 < S_CHUNK)
            atomicAdd(&bins[j1], e.y * s_scales[TY(cc.y) * NUM_TYPES + TY(nn.y)]);
        if (j2 < S_CHUNK)
            atomicAdd(&bins[j2], e.z * s_scales[TY(cc.z) * NUM_TYPES + TY(nn.z)]);
        if (j3 < S_CHUNK)
            atomicAdd(&bins[j3], e.w * s_scales[TY(cc.w) * NUM_TYPES + TY(nn.w)]);
    }

    // tail (E % 4) — dead for E = 6,400,000; b==0 occurs once per chunk
    // (x=0, o=0..3 -> c=0..3, b=0)
    if (b == 0) {
        for (int i = (n4 << 2) + (int)threadIdx.x; i < E; i += THR) {
            int cn = centers[i];
            unsigned j = (unsigned)(cn - base);
            if (j < S_CHUNK)
                atomicAdd(&bins[j], eng[i] * s_scales[TY(cn) * NUM_TYPES + TY(neighbors[i])]);
        }
    }
#undef TY

    __syncthreads();
    float4* dst4 = (float4*)(partials + ((size_t)c * B + b) * S_CHUNK);
    for (int j = threadIdx.x; j < S_CHUNK / 4; j += THR) dst4[j] = bins4[j];
}

// ---------- Kernel 2: reduce segment partials (float4) ----------
__global__ __launch_bounds__(256) void reduce_kernel(
    const float* __restrict__ partials, float* __restrict__ out, int B, int N4)
{
    int t = blockIdx.x * blockDim.x + threadIdx.x;
    if (t >= N4) return;
    int n = t * 4;
    int c = n / S_CHUNK;
    int j = n - c * S_CHUNK;
    const float4* p = (const float4*)(partials + ((size_t)c * B) * S_CHUNK + j);
    float4 s = make_float4(0.f, 0.f, 0.f, 0.f);
    for (int b = 0; b < B; ++b) {
        float4 v = p[(size_t)b * (S_CHUNK / 4)];
        s.x += v.x; s.y += v.y; s.z += v.z; s.w += v.w;
    }
    ((float4*)out)[t] = s;
}

__global__ __launch_bounds__(256) void reduce_scalar_kernel(
    const float* __restrict__ partials, float* __restrict__ out, int B, int N)
{
    int n = blockIdx.x * blockDim.x + threadIdx.x;
    if (n >= N) return;
    int c = n / S_CHUNK;
    int j = n - c * S_CHUNK;
    const float* p = partials + ((size_t)c * B) * S_CHUNK + j;
    float s = 0.0f;
    for (int b = 0; b < B; ++b) s += p[(size_t)b * S_CHUNK];
    out[n] = s;
}

// ---------- Fallback (tiny workspace only): direct atomic scatter ----------
__global__ __launch_bounds__(256) void edge_sum_atomic_kernel(
    const int* __restrict__ centers, const int* __restrict__ neighbors,
    const float* __restrict__ eng, const int* __restrict__ atom_type,
    const float* __restrict__ scales, float* __restrict__ out, int E)
{
    __shared__ float s_scales[NUM_TYPES * NUM_TYPES];
    if (threadIdx.x < NUM_TYPES * NUM_TYPES) s_scales[threadIdx.x] = scales[threadIdx.x];
    __syncthreads();
    int tid = blockIdx.x * blockDim.x + threadIdx.x;
    int stride = gridDim.x * blockDim.x;
    for (int i = tid; i < E; i += stride) {
        int cn = centers[i];
        float v = eng[i] * s_scales[atom_type[cn] * NUM_TYPES + atom_type[neighbors[i]]] * FACTOR;
        unsafeAtomicAdd(&out[cn], v);
    }
}

extern "C" void kernel_launch(void* const* d_in, const int* in_sizes, int n_in,
                              void* d_out, int out_size, void* d_ws, size_t ws_size,
                              hipStream_t stream) {
    const int E = in_sizes[1];  // edge_eng element count
    const int N = in_sizes[2];  // atom_type element count
    const int* edge_index = (const int*)d_in[0];   // [2, E]
    const float* edge_eng = (const float*)d_in[1]; // [E, 1]
    const int* atom_type = (const int*)d_in[2];    // [N, 1]
    const float* scales = (const float*)d_in[3];   // [T, T]
    float* out = (float*)d_out;

    const int* centers = edge_index;
    const int* neighbors = edge_index + E;

    // ws layout: [tt4: C*S/2 u8 (aligned)][partials: C*B*S_CHUNK floats]
    auto al = [](size_t v) { return (v + 255) & ~(size_t)255; };
    size_t tt4_sz = al((size_t)C_CHUNKS * S_CHUNK / 2);           // 50 KB
    size_t per_b  = (size_t)C_CHUNKS * S_CHUNK * sizeof(float);   // 409.6 KB per segment

    int B = 0;
    if (N <= C_CHUNKS * S_CHUNK && ws_size > tt4_sz)
        B = (int)((ws_size - tt4_sz) / per_b);
    if (B > B_TARGET) B = B_TARGET;
    B &= ~7;   // XCD-local mapping requires B % 8 == 0

    if (B >= 8) {
        unsigned char* tt4 = (unsigned char*)d_ws;
        float* partials    = (float*)((char*)d_ws + tt4_sz);
        type_pack_kernel<<<(C_CHUNKS * S_CHUNK / 2 + 255) / 256, 256, 0, stream>>>(
            atom_type, tt4, N);
        fused_chunk_sum_kernel<<<C_CHUNKS * B, THR, 0, stream>>>(
            centers, neighbors, edge_eng, tt4, scales, partials, E, B);
        if ((N & 3) == 0)
            reduce_kernel<<<(N / 4 + 255) / 256, 256, 0, stream>>>(partials, out, B, N / 4);
        else
            reduce_scalar_kernel<<<(N + 255) / 256, 256, 0, stream>>>(partials, out, B, N);
    } else {
        hipMemsetAsync(d_out, 0, (size_t)out_size * sizeof(float), stream);
        edge_sum_atomic_kernel<<<2048, 256, 0, stream>>>(
            centers, neighbors, edge_eng, atom_type, scales, out, E);
    }
}

// Round 13
// 156.363 us; speedup vs baseline: 1.1085x; 1.0253x over previous
//
#include <hip/hip_runtime.h>

#define N_NODES 100000
#define NUM_TYPES 8
#define FACTOR 0.125f      // 1/sqrt(64)

#define S_CHUNK 25600      // nodes per chunk; bins 100 KB + full tt4 50 KB = 153.9 KB LDS
#define C_CHUNKS 4         // 4*25600 = 102400 >= 100000
#define THR 1024
#define B_TARGET 64        // grid = 4*64 = 256 blocks (1/CU)
#define NXCD 8             // blockIdx % 8 ~ XCD under round-robin dispatch

// ---------- Kernel 0: pack atom_type into nibble table (50 KB) ----------
__global__ __launch_bounds__(256) void type_pack_kernel(
    const int* __restrict__ atom_type, unsigned char* __restrict__ tt4, int N)
{
    int i = blockIdx.x * blockDim.x + threadIdx.x;   // nibble-pair index
    if (i >= C_CHUNKS * S_CHUNK / 2) return;
    int n0 = 2 * i, n1 = 2 * i + 1;
    unsigned char t0 = (n0 < N) ? (unsigned char)atom_type[n0] : 0;
    unsigned char t1 = (n1 < N) ? (unsigned char)atom_type[n1] : 0;
    tt4[i] = (unsigned char)(t0 | (t1 << 4));
}

// ---------- Kernel 1: fused chunk-sum, all-LDS lookups, x2 unrolled ----------
// r12 diagnosis: 58.5 us = ~30 us pipe work + ~27 us LDS dependency stall
// (3-deep chain nibble->scale->ds_add at ~100cyc/hop, only 4 waves/SIMD since
// 154 KB LDS caps 1 block/CU). Fix: x2 manual unroll -> 8 independent edge
// chains per thread (2x MLP/ILP), zero LDS cost. Mapping (r10, -4x FETCH):
// x=blk&7, o=blk>>3, c=o&3, b=x*(B/8)+(o>>2) keeps a segment's 4 chunk-blocks
// on one XCD. All random traffic is LDS (50 KB nibble type table + bins).
__global__ __launch_bounds__(THR) void fused_chunk_sum_kernel(
    const int* __restrict__ centers,
    const int* __restrict__ neighbors,
    const float* __restrict__ eng,
    const unsigned char* __restrict__ tt4,  // [C*S/2] nibble-packed types (padded)
    const float* __restrict__ scales,
    float* __restrict__ partials,           // [C_CHUNKS][B][S_CHUNK]
    int E, int B)
{
    __shared__ __align__(16) float bins[S_CHUNK];
    __shared__ __align__(16) unsigned char s_tt4[C_CHUNKS * S_CHUNK / 2];  // 50 KB
    __shared__ float s_scales[NUM_TYPES * NUM_TYPES];

    const int x = blockIdx.x & (NXCD - 1);   // XCD id (round-robin dispatch)
    const int o = blockIdx.x >> 3;           // ordinal within XCD
    const int c = o & 3;                     // chunk
    const int b = x * (B >> 3) + (o >> 2);   // edge segment (B % 8 == 0)
    const int base = c * S_CHUNK;

    if (threadIdx.x < NUM_TYPES * NUM_TYPES)
        s_scales[threadIdx.x] = scales[threadIdx.x] * FACTOR;   // fold FACTOR

    float4* bins4 = (float4*)bins;
    for (int j = threadIdx.x; j < S_CHUNK / 4; j += THR)
        bins4[j] = make_float4(0.f, 0.f, 0.f, 0.f);
    {   // stage full nibble table: 51 200 B = 3200 uint4
        const uint4* src = (const uint4*)tt4;
        uint4* dst = (uint4*)s_tt4;
        for (int j = threadIdx.x; j < C_CHUNKS * S_CHUNK / 2 / 16; j += THR)
            dst[j] = src[j];
    }
    __syncthreads();

    const int n4 = E >> 2;

// type of global node index G from the LDS nibble table
#define TY(G)  (int)((s_tt4[(unsigned)(G) >> 1] >> (((unsigned)(G) & 1u) << 2)) & 7u)
#define BODY(CC, NN, EE) { \
        unsigned j0 = (unsigned)((CC).x - base); \
        unsigned j1 = (unsigned)((CC).y - base); \
        unsigned j2 = (unsigned)((CC).z - base); \
        unsigned j3 = (unsigned)((CC).w - base); \
        if (j0 < S_CHUNK) atomicAdd(&bins[j0], (EE).x * s_scales[TY((CC).x) * NUM_TYPES + TY((NN).x)]); \
        if (j1 < S_CHUNK) atomicAdd(&bins[j1], (EE).y * s_scales[TY((CC).y) * NUM_TYPES + TY((NN).y)]); \
        if (j2 < S_CHUNK) atomicAdd(&bins[j2], (EE).z * s_scales[TY((CC).z) * NUM_TYPES + TY((NN).z)]); \
        if (j3 < S_CHUNK) atomicAdd(&bins[j3], (EE).w * s_scales[TY((CC).w) * NUM_TYPES + TY((NN).w)]); }

    // x2-unrolled sweep: block-tile of 2*THR quads per stride; both halves
    // hoisted up front -> 8 independent edge chains in flight per thread.
    for (int i = b * (2 * THR) + (int)threadIdx.x; i < n4; i += B * (2 * THR)) {
        int4   cc0 = ((const int4*)centers)[i];
        int4   nn0 = ((const int4*)neighbors)[i];
        float4 e0  = ((const float4*)eng)[i];
        const int i1 = i + THR;
        const bool has1 = (i1 < n4);
        int4 cc1, nn1; float4 e1;
        if (has1) {
            cc1 = ((const int4*)centers)[i1];
            nn1 = ((const int4*)neighbors)[i1];
            e1  = ((const float4*)eng)[i1];
        }
        BODY(cc0, nn0, e0)
        if (has1) BODY(cc1, nn1, e1)
    }

    // tail (E % 4) — dead for E = 6,400,000; b==0 occurs once per chunk
    // (x=0, o=0..3 -> c=0..3, b=0)
    if (b == 0) {
        for (int i = (n4 << 2) + (int)threadIdx.x; i < E; i += THR) {
            int cn = centers[i];
            unsigned j = (unsigned)(cn - base);
            if (j < S_CHUNK)
                atomicAdd(&bins[j], eng[i] * s_scales[TY(cn) * NUM_TYPES + TY(neighbors[i])]);
        }
    }
#undef BODY
#undef TY

    __syncthreads();
    float4* dst4 = (float4*)(partials + ((size_t)c * B + b) * S_CHUNK);
    for (int j = threadIdx.x; j < S_CHUNK / 4; j += THR) dst4[j] = bins4[j];
}

// ---------- Kernel 2: reduce segment partials (float4) ----------
__global__ __launch_bounds__(256) void reduce_kernel(
    const float* __restrict__ partials, float* __restrict__ out, int B, int N4)
{
    int t = blockIdx.x * blockDim.x + threadIdx.x;
    if (t >= N4) return;
    int n = t * 4;
    int c = n / S_CHUNK;
    int j = n - c * S_CHUNK;
    const float4* p = (const float4*)(partials + ((size_t)c * B) * S_CHUNK + j);
    float4 s = make_float4(0.f, 0.f, 0.f, 0.f);
    for (int b = 0; b < B; ++b) {
        float4 v = p[(size_t)b * (S_CHUNK / 4)];
        s.x += v.x; s.y += v.y; s.z += v.z; s.w += v.w;
    }
    ((float4*)out)[t] = s;
}

__global__ __launch_bounds__(256) void reduce_scalar_kernel(
    const float* __restrict__ partials, float* __restrict__ out, int B, int N)
{
    int n = blockIdx.x * blockDim.x + threadIdx.x;
    if (n >= N) return;
    int c = n / S_CHUNK;
    int j = n - c * S_CHUNK;
    const float* p = partials + ((size_t)c * B) * S_CHUNK + j;
    float s = 0.0f;
    for (int b = 0; b < B; ++b) s += p[(size_t)b * S_CHUNK];
    out[n] = s;
}

// ---------- Fallback (tiny workspace only): direct atomic scatter ----------
__global__ __launch_bounds__(256) void edge_sum_atomic_kernel(
    const int* __restrict__ centers, const int* __restrict__ neighbors,
    const float* __restrict__ eng, const int* __restrict__ atom_type,
    const float* __restrict__ scales, float* __restrict__ out, int E)
{
    __shared__ float s_scales[NUM_TYPES * NUM_TYPES];
    if (threadIdx.x < NUM_TYPES * NUM_TYPES) s_scales[threadIdx.x] = scales[threadIdx.x];
    __syncthreads();
    int tid = blockIdx.x * blockDim.x + threadIdx.x;
    int stride = gridDim.x * blockDim.x;
    for (int i = tid; i < E; i += stride) {
        int cn = centers[i];
        float v = eng[i] * s_scales[atom_type[cn] * NUM_TYPES + atom_type[neighbors[i]]] * FACTOR;
        unsafeAtomicAdd(&out[cn], v);
    }
}

extern "C" void kernel_launch(void* const* d_in, const int* in_sizes, int n_in,
                              void* d_out, int out_size, void* d_ws, size_t ws_size,
                              hipStream_t stream) {
    const int E = in_sizes[1];  // edge_eng element count
    const int N = in_sizes[2];  // atom_type element count
    const int* edge_index = (const int*)d_in[0];   // [2, E]
    const float* edge_eng = (const float*)d_in[1]; // [E, 1]
    const int* atom_type = (const int*)d_in[2];    // [N, 1]
    const float* scales = (const float*)d_in[3];   // [T, T]
    float* out = (float*)d_out;

    const int* centers = edge_index;
    const int* neighbors = edge_index + E;

    // ws layout: [tt4: C*S/2 u8 (aligned)][partials: C*B*S_CHUNK floats]
    auto al = [](size_t v) { return (v + 255) & ~(size_t)255; };
    size_t tt4_sz = al((size_t)C_CHUNKS * S_CHUNK / 2);           // 50 KB
    size_t per_b  = (size_t)C_CHUNKS * S_CHUNK * sizeof(float);   // 409.6 KB per segment

    int B = 0;
    if (N <= C_CHUNKS * S_CHUNK && ws_size > tt4_sz)
        B = (int)((ws_size - tt4_sz) / per_b);
    if (B > B_TARGET) B = B_TARGET;
    B &= ~7;   // XCD-local mapping requires B % 8 == 0

    if (B >= 8) {
        unsigned char* tt4 = (unsigned char*)d_ws;
        float* partials    = (float*)((char*)d_ws + tt4_sz);
        type_pack_kernel<<<(C_CHUNKS * S_CHUNK / 2 + 255) / 256, 256, 0, stream>>>(
            atom_type, tt4, N);
        fused_chunk_sum_kernel<<<C_CHUNKS * B, THR, 0, stream>>>(
            centers, neighbors, edge_eng, tt4, scales, partials, E, B);
        if ((N & 3) == 0)
            reduce_kernel<<<(N / 4 + 255) / 256, 256, 0, stream>>>(partials, out, B, N / 4);
        else
            reduce_scalar_kernel<<<(N + 255) / 256, 256, 0, stream>>>(partials, out, B, N);
    } else {
        hipMemsetAsync(d_out, 0, (size_t)out_size * sizeof(float), stream);
        edge_sum_atomic_kernel<<<2048, 256, 0, stream>>>(
            centers, neighbors, edge_eng, atom_type, scales, out, E);
    }
}